// Round 11
// baseline (114.175 us; speedup 1.0000x reference)
//
#include <hip/hip_runtime.h>
#include <hip/hip_bf16.h>

// Problem constants (match reference)
#define B_   8
#define NQ_  64     // N_CANDS
#define CTX_ 512    // CTX_LEN
#define DC_  512    // CONTEXT_SIZE
#define DQ_  512    // QUERY_SIZE
#define H_   256    // HIDDEN
#define EPS_ 1e-5f

using short8  = __attribute__((ext_vector_type(8))) short;  // 8 bf16 (4 VGPRs)
using floatx4 = __attribute__((ext_vector_type(4))) float;  // MFMA acc

// 2 fp32 -> packed bf16x2 via v_cvt_pk_bf16_f32 (single instruction on gfx950)
__device__ __forceinline__ unsigned pk2(float x, float y) {
    union { __hip_bfloat162 h; unsigned u; } c;
    c.h = __float22bfloat162_rn(make_float2(x, y));
    return c.u;
}
// 8 fp32 (two float4) -> 16B packed bf16
__device__ __forceinline__ uint4 cvt8u(float4 a, float4 b) {
    uint4 r;
    r.x = pk2(a.x, a.y); r.y = pk2(a.z, a.w);
    r.z = pk2(b.x, b.y); r.w = pk2(b.z, b.w);
    return r;
}

// ---------------------------------------------------------------------------
// Kernel 1 (unchanged, known-good from the 108.6 µs config): both input GEMMs
// via bf16 MFMA, LDS-staged with register prefetch. Epilogue:
// Ec = exp(2*(acc+bias)), Eq = exp(2*acc)  (factored-exp: tanh(x)=1-2/(e^2x+1)).
// Tile 32Mx64N, BK=64; grid 144x4 = 576 blocks.
// ---------------------------------------------------------------------------
__global__ __launch_bounds__(256) void gemm_exp(
    const float* __restrict__ ctx, const float* __restrict__ query,
    const float* __restrict__ W_c, const float* __restrict__ b_c,
    const float* __restrict__ W_q,
    float* __restrict__ Ec, float* __restrict__ Eq)
{
    __shared__ unsigned short As[32][72];   // 32 rows x 64 bf16 (+8 pad)
    __shared__ unsigned short Bs[64][72];   // 64 rows x 64 bf16 (+8 pad)

    const int rt = blockIdx.x;     // 0..143 (128 ctx + 16 query row-tiles)
    const int ct = blockIdx.y;     // 0..3

    const float* A; const float* W; const float* bias; float* outp; int row0;
    if (rt < 128) { A = ctx;   W = W_c; bias = b_c;     outp = Ec; row0 = rt * 32; }
    else          { A = query; W = W_q; bias = nullptr; outp = Eq; row0 = (rt - 128) * 32; }

    const int col0 = ct * 64;
    const int t    = threadIdx.x;
    const int wave = t >> 6;
    const int lane = t & 63;
    const int m  = lane & 15;
    const int kq = lane >> 4;
    const int mh = wave >> 1;      // M-half: rows mh*16..+16
    const int nh = wave & 1;       // N-half: cols nh*32..+32

    const int sr = t >> 3, ss = t & 7;
    const float* gA  = A + (size_t)(row0 + sr) * 512 + ss * 8;
    const float* gB0 = W + (size_t)(col0 + sr) * 512 + ss * 8;
    const float* gB1 = W + (size_t)(col0 + 32 + sr) * 512 + ss * 8;
    unsigned short* lA  = &As[sr][ss * 8];
    unsigned short* lB0 = &Bs[sr][ss * 8];
    unsigned short* lB1 = &Bs[32 + sr][ss * 8];

    floatx4 acc[2] = {};
    float4 pA0, pA1, pB00, pB01, pB10, pB11;

    pA0  = *(const float4*)(gA);       pA1  = *(const float4*)(gA + 4);
    pB00 = *(const float4*)(gB0);      pB01 = *(const float4*)(gB0 + 4);
    pB10 = *(const float4*)(gB1);      pB11 = *(const float4*)(gB1 + 4);

    for (int s = 0; s < 8; ++s) {
        __syncthreads();
        *(uint4*)lA  = cvt8u(pA0, pA1);
        *(uint4*)lB0 = cvt8u(pB00, pB01);
        *(uint4*)lB1 = cvt8u(pB10, pB11);
        __syncthreads();

        if (s < 7) {
            const int k = (s + 1) * 64;
            pA0  = *(const float4*)(gA + k);   pA1  = *(const float4*)(gA + k + 4);
            pB00 = *(const float4*)(gB0 + k);  pB01 = *(const float4*)(gB0 + k + 4);
            pB10 = *(const float4*)(gB1 + k);  pB11 = *(const float4*)(gB1 + k + 4);
        }

        #pragma unroll
        for (int kc = 0; kc < 2; ++kc) {
            short8 af = *(const short8*)&As[mh * 16 + m][kc * 32 + kq * 8];
            short8 b0 = *(const short8*)&Bs[nh * 32 +      m][kc * 32 + kq * 8];
            short8 b1 = *(const short8*)&Bs[nh * 32 + 16 + m][kc * 32 + kq * 8];
            acc[0] = __builtin_amdgcn_mfma_f32_16x16x32_bf16(af, b0, acc[0], 0, 0, 0);
            acc[1] = __builtin_amdgcn_mfma_f32_16x16x32_bf16(af, b1, acc[1], 0, 0, 0);
        }
    }

    #pragma unroll
    for (int j = 0; j < 2; ++j) {
        const int col = col0 + nh * 32 + j * 16 + m;
        const float bb = bias ? bias[col] : 0.f;
        #pragma unroll
        for (int i = 0; i < 4; ++i) {
            const int row = row0 + mh * 16 + kq * 4 + i;
            outp[(size_t)row * H_ + col] = __expf(2.f * (acc[j][i] + bb));
        }
    }
}

// ---------------------------------------------------------------------------
// Kernel 2: scoring + partial output. Grid 512 = b(8) x ctile(8: 64c) x
// qgroup(8: 8q). Lane owns one c, wave owns a q-pair (identical scoring math
// to the 108.6 config). Then the block's 64c x 8q e-tile (stashed in LDS)
// is immediately used for the partial weighted context sum over its c-range:
//   outP[ctile][b,qg][q][d] = sum_{c in tile} e[q,c] * ctx[b,c,d]
// plus per-q partial denominators (64-lane butterfly) to denomP.
// ---------------------------------------------------------------------------
__global__ __launch_bounds__(256) void score_out(
    const float* __restrict__ Ec,    // B*CTX*H
    const float* __restrict__ Eqm,   // B*NQ*H
    const float* __restrict__ W_o,   // H
    const float* __restrict__ b_o_p, // scalar
    const float* __restrict__ mask,  // B*CTX
    const float* __restrict__ ctx,   // B*CTX*DC
    float* __restrict__ eout,        // B*NQ*CTX
    float* __restrict__ denomP,      // (B*8qg*8q) * 8ct
    float* __restrict__ outP)        // 8ct * (B*8qg) * 8q * DC
{
    __shared__ float eqs[8][H_];     // 8 KB
    __shared__ float wos[H_];        // 1 KB
    __shared__ float ecs[64][133];   // 64c x 128h half-chunk, pad->2-way max
    __shared__ float em[64][12];     // e-tile [c][q], 16B-aligned rows
    __shared__ float redS[4];

    const int blk = blockIdx.x;
    const int b  = blk & 7;          // XCD swizzle
    const int ctile = (blk >> 3) & 7;
    const int qg = blk >> 6;
    const int t  = threadIdx.x;

    // stage Eq rows (8 q x 256 h) + W_o, coalesced
    const float* eqb = Eqm + (size_t)(b * NQ_ + qg * 8) * H_;
    #pragma unroll
    for (int i = 0; i < 8; ++i) ((float*)eqs)[t + 256 * i] = eqb[t + 256 * i];
    const float wo_own = W_o[t];
    wos[t] = wo_own;
    float S = wo_own;
    #pragma unroll
    for (int k = 1; k < 64; k <<= 1) S += __shfl_xor(S, k);
    if ((t & 63) == 0) redS[t >> 6] = S;

    const int cl = t & 63;           // lane's c within 64-c tile
    const int qi = t >> 6;           // wave's q-pair (0..3)
    const int c0 = ctile * 64;
    const float* ec_tile = Ec + (size_t)(b * CTX_ + c0) * H_;
    // staging map: row = t>>2 (4 thr/row), each thread 8 float4 at cols
    // (t&3)*4 + j*16  (coalesced 64B per 4 threads; LDS banks spread)
    const int srow = t >> 2, scol = (t & 3) * 4;
    const float* eqa = eqs[qi * 2];
    const float* eqc = eqs[qi * 2 + 1];

    float s0 = 0.f, s1 = 0.f;
    for (int half = 0; half < 2; ++half) {
        const float* src = ec_tile + (size_t)srow * H_ + half * 128 + scol;
        float4 v[8];
        #pragma unroll
        for (int j = 0; j < 8; ++j) v[j] = *(const float4*)(src + j * 16);
        __syncthreads();             // prior half's readers done (covers eqs/redS)
        #pragma unroll
        for (int j = 0; j < 8; ++j)
            *(float4*)&ecs[srow][scol + j * 16] = v[j];
        __syncthreads();
        const int ho = half * 128;
        #pragma unroll
        for (int h4 = 0; h4 < 32; ++h4) {
            float4 ea = *(const float4*)&ecs[cl][h4 * 4];       // LDS per-lane
            float4 qa = *(const float4*)(eqa + ho + h4 * 4);    // LDS broadcast
            float4 qc = *(const float4*)(eqc + ho + h4 * 4);    // LDS broadcast
            float4 w4 = *(const float4*)(wos + ho + h4 * 4);    // LDS broadcast
            s0 += w4.x * __builtin_amdgcn_rcpf(ea.x * qa.x + 1.f);
            s0 += w4.y * __builtin_amdgcn_rcpf(ea.y * qa.y + 1.f);
            s0 += w4.z * __builtin_amdgcn_rcpf(ea.z * qa.z + 1.f);
            s0 += w4.w * __builtin_amdgcn_rcpf(ea.w * qa.w + 1.f);
            s1 += w4.x * __builtin_amdgcn_rcpf(ea.x * qc.x + 1.f);
            s1 += w4.y * __builtin_amdgcn_rcpf(ea.y * qc.y + 1.f);
            s1 += w4.z * __builtin_amdgcn_rcpf(ea.z * qc.z + 1.f);
            s1 += w4.w * __builtin_amdgcn_rcpf(ea.w * qc.w + 1.f);
        }
    }

    const float base = *b_o_p + redS[0] + redS[1] + redS[2] + redS[3];
    const int c = c0 + cl;
    const float mk = mask[b * CTX_ + c];
    const float e0 = mk * __expf(base - 2.f * s0);
    const float e1 = mk * __expf(base - 2.f * s1);
    const int q = b * NQ_ + qg * 8 + qi * 2;
    eout[(size_t)q * CTX_ + c]       = e0;
    eout[(size_t)(q + 1) * CTX_ + c] = e1;
    *(float2*)&em[cl][qi * 2] = make_float2(e0, e1);

    // partial denominators over this 64-c tile (per q): full-wave butterfly
    float d0 = e0, d1 = e1;
    #pragma unroll
    for (int k = 1; k < 64; k <<= 1) {
        d0 += __shfl_xor(d0, k);
        d1 += __shfl_xor(d1, k);
    }
    if (cl == 0) {
        const int qb = ((b * 8 + qg) * 8 + qi * 2) * 8;
        denomP[qb + ctile]     = d0;
        denomP[qb + 8 + ctile] = d1;
    }
    __syncthreads();                 // em ready

    // partial output: thread owns d = 2t, 2t+1; loop the tile's 64 c
    const float* cb = ctx + ((size_t)(b * CTX_) + c0) * DC_ + t * 2;
    float2 acc[8];
    #pragma unroll
    for (int j = 0; j < 8; ++j) acc[j] = make_float2(0.f, 0.f);
    #pragma unroll 4
    for (int cc = 0; cc < 64; ++cc) {
        const float4 eA = *(const float4*)&em[cc][0];   // broadcast
        const float4 eB = *(const float4*)&em[cc][4];   // broadcast
        const float2 v = *(const float2*)(cb + (size_t)cc * DC_);
        acc[0].x += eA.x * v.x; acc[0].y += eA.x * v.y;
        acc[1].x += eA.y * v.x; acc[1].y += eA.y * v.y;
        acc[2].x += eA.z * v.x; acc[2].y += eA.z * v.y;
        acc[3].x += eA.w * v.x; acc[3].y += eA.w * v.y;
        acc[4].x += eB.x * v.x; acc[4].y += eB.x * v.y;
        acc[5].x += eB.y * v.x; acc[5].y += eB.y * v.y;
        acc[6].x += eB.z * v.x; acc[6].y += eB.z * v.y;
        acc[7].x += eB.w * v.x; acc[7].y += eB.w * v.y;
    }
    float* op = outP + (((size_t)(ctile * 64 + b * 8 + qg)) * 8) * DC_ + t * 2;
    #pragma unroll
    for (int j = 0; j < 8; ++j)
        *(float2*)(op + (size_t)j * DC_) = acc[j];
}

// ---------------------------------------------------------------------------
// Kernel 3: reduce. Grid 512 = b(8) x qgroup(8) x dq(8: 64d).
// invs from 8 denomP partials per q (reference-exact: denom = sum + EPS);
// out = (sum of 8 ctile partials) * inv; wout = eout * inv (dq==0 blocks).
// ---------------------------------------------------------------------------
__global__ __launch_bounds__(256) void reduce_kernel(
    const float* __restrict__ eout,    // B*NQ*CTX
    const float* __restrict__ denomP,  // (B*8*8) * 8
    const float* __restrict__ outP,    // 8 * (B*8) * 8 * DC
    float* __restrict__ out,           // B*NQ*DC
    float* __restrict__ wout)          // B*NQ*CTX
{
    __shared__ float invs[8];

    const int blk = blockIdx.x;
    const int b  = blk & 7;
    const int qg = (blk >> 3) & 7;
    const int dq = blk >> 6;           // 0..7: d in [dq*64, +64)
    const int t  = threadIdx.x;

    if (t < 8) {
        const float* dp = denomP + ((size_t)((b * 8 + qg) * 8 + t)) * 8;
        float s = EPS_;
        #pragma unroll
        for (int j = 0; j < 8; ++j) s += dp[j];
        invs[t] = 1.f / s;
    }
    __syncthreads();

    if (dq == 0) {                     // wout = e * inv (one block per (b,qg))
        const int qi = t >> 5, cl = t & 31;
        const int q = b * NQ_ + qg * 8 + qi;
        const float inv = invs[qi];
        const float* erow = eout + (size_t)q * CTX_;
        #pragma unroll
        for (int k = 0; k < 16; ++k) {
            const int c = cl + 32 * k;
            wout[(size_t)q * CTX_ + c] = erow[c] * inv;
        }
    }

    // sum 8 ctile partials; thread owns (q = t>>5, d = dq*64 + (t&31)*2)
    const int q  = t >> 5;
    const int d  = dq * 64 + (t & 31) * 2;
    const float* pp = outP + (((size_t)(b * 8 + qg)) * 8 + q) * DC_ + d;
    float2 s = make_float2(0.f, 0.f);
    #pragma unroll
    for (int ct = 0; ct < 8; ++ct) {
        const float2 p = *(const float2*)(pp + (size_t)(ct * 64 * 8) * DC_);
        s.x += p.x; s.y += p.y;
    }
    const float inv = invs[q];
    const int gq = b * NQ_ + qg * 8 + q;
    *(float2*)&out[(size_t)gq * DC_ + d] = make_float2(s.x * inv, s.y * inv);
}

extern "C" void kernel_launch(void* const* d_in, const int* in_sizes, int n_in,
                              void* d_out, int out_size, void* d_ws, size_t ws_size,
                              hipStream_t stream) {
    const float* query   = (const float*)d_in[0];  // B,NQ,DQ
    const float* context = (const float*)d_in[1];  // B,CTX,DC
    const float* mask    = (const float*)d_in[2];  // B,CTX
    const float* W_c     = (const float*)d_in[3];  // H,DC
    const float* b_c     = (const float*)d_in[4];  // H
    const float* W_q     = (const float*)d_in[5];  // H,DQ
    const float* W_o     = (const float*)d_in[6];  // H
    const float* b_o     = (const float*)d_in[7];  // scalar

    float* out  = (float*)d_out;                   // B,NQ,DC
    float* wout = out + (size_t)B_ * NQ_ * DC_;    // B,NQ,CTX

    float* Ec     = (float*)d_ws;                      // 4 MB: exp(2*res_c)
    float* Eq     = Ec + (size_t)B_ * CTX_ * H_;       // 512 KB: exp(2*res_q)
    float* eout   = Eq + (size_t)B_ * NQ_ * H_;        // 1 MB
    float* denomP = eout + (size_t)B_ * NQ_ * CTX_;    // 16 KB
    float* outP   = denomP + 4096;                     // 8 MB partial sums

    gemm_exp<<<dim3(144, 4), 256, 0, stream>>>(
        context, query, W_c, b_c, W_q, Ec, Eq);
    score_out<<<512, 256, 0, stream>>>(
        Ec, Eq, W_o, b_o, mask, context, eout, denomP, outP);
    reduce_kernel<<<512, 256, 0, stream>>>(
        eout, denomP, outP, out, wout);
}